// Round 2
// baseline (8988.355 us; speedup 1.0000x reference)
//
#include <hip/hip_runtime.h>

#define B_ 1024
#define T_ 100
#define F_ 300
#define FP_ 320
#define U_ 512
#define G4_ 2048
#define C_ 10
#define EPS_ 1e-3f

typedef _Float16 f16x8 __attribute__((ext_vector_type(8)));
typedef float f32x4 __attribute__((ext_vector_type(4)));

// ---------------- prologue kernels ----------------

// x (B,T,F) fp32 -> x_hi/x_lo [T][B][FP_] fp16 split, zero-padded F..FP_
__global__ __launch_bounds__(256) void cast_x_kernel(const float* __restrict__ x,
                                                     _Float16* __restrict__ xhi,
                                                     _Float16* __restrict__ xlo) {
  size_t idx = (size_t)blockIdx.x * 256 + threadIdx.x;
  int f = (int)(idx % FP_);
  size_t bt = idx / FP_;
  int b = (int)(bt % B_);
  int t = (int)(bt / B_);
  float v = 0.f;
  if (f < F_) v = x[((size_t)b * T_ + t) * F_ + f];
  _Float16 h = (_Float16)v;
  xhi[idx] = h;
  xlo[idx] = (_Float16)(v - (float)h);
}

// W [K][N] fp32 -> Wt_hi/Wt_lo [N][Kp] fp16 split (transposed, zero-padded K..Kp)
__global__ __launch_bounds__(256) void cast_w_kernel(const float* __restrict__ W,
                                                     _Float16* __restrict__ Whi,
                                                     _Float16* __restrict__ Wlo,
                                                     int K, int N, int Kp) {
  __shared__ float tile[32][33];
  int n0 = blockIdx.x * 32, k0 = blockIdx.y * 32;
  int tx = threadIdx.x & 31, ty = threadIdx.x >> 5;
#pragma unroll
  for (int r = 0; r < 32; r += 8) {
    int k = k0 + ty + r;
    tile[ty + r][tx] = (k < K) ? W[(size_t)k * N + n0 + tx] : 0.f;
  }
  __syncthreads();
#pragma unroll
  for (int r = 0; r < 32; r += 8) {
    int n = n0 + ty + r, kk = k0 + tx;
    if (kk < Kp) {
      float v = tile[tx][ty + r];
      _Float16 h = (_Float16)v;
      Whi[(size_t)n * Kp + kk] = h;
      Wlo[(size_t)n * Kp + kk] = (_Float16)(v - (float)h);
    }
  }
}

// ---------------- GEMM: G = A (MxK) * Bt^T (Bt is [N][K]) -> G [M][2048] fp32 ----------------
// Split-fp16: A = A_hi + A_lo (A_lo at A + aLo elements), Bt likewise (lo at + N*K).
// Computes A_hi@B_hi + A_lo@B_hi + A_hi@B_lo  (3 K-segments; dropped lo*lo ~ 2^-24).
// 64x64 block tile, 4 waves, each wave 16(m) x 64(n), mfma 16x16x32 f16.
// Up to 3 independent GEMMs selected by blockIdx.z.
__global__ __launch_bounds__(256) void gemm3_kernel(
    const _Float16* __restrict__ A0, const _Float16* __restrict__ Bt0, float* __restrict__ G0, int lda0, int K0, size_t aLo0,
    const _Float16* __restrict__ A1, const _Float16* __restrict__ Bt1, float* __restrict__ G1, int lda1, int K1, size_t aLo1,
    const _Float16* __restrict__ A2, const _Float16* __restrict__ Bt2, float* __restrict__ G2, int lda2, int K2, size_t aLo2) {
  const _Float16* A;
  const _Float16* Bt;
  float* G;
  int lda, K;
  size_t aLo;
  if (blockIdx.z == 0) { A = A0; Bt = Bt0; G = G0; lda = lda0; K = K0; aLo = aLo0; }
  else if (blockIdx.z == 1) { A = A1; Bt = Bt1; G = G1; lda = lda1; K = K1; aLo = aLo1; }
  else { A = A2; Bt = Bt2; G = G2; lda = lda2; K = K2; aLo = aLo2; }

  __shared__ __align__(16) _Float16 as[64][40];  // 80B row stride: 16B aligned, <=2-way bank alias
  __shared__ __align__(16) _Float16 bs[64][40];

  int tid = threadIdx.x;
  int lane = tid & 63, w = tid >> 6;
  int mBase = blockIdx.y * 64, nBase = blockIdx.x * 64;
  int lrow = tid >> 2, lch = (tid & 3) * 8;

  f32x4 acc[4] = {{0.f, 0.f, 0.f, 0.f}, {0.f, 0.f, 0.f, 0.f}, {0.f, 0.f, 0.f, 0.f}, {0.f, 0.f, 0.f, 0.f}};

  const size_t bLo = (size_t)G4_ * K;
#pragma unroll 1
  for (int s = 0; s < 3; s++) {
    const _Float16* Ap = A + ((s == 1) ? aLo : 0);
    const _Float16* Bp = Bt + ((s == 2) ? bLo : 0);
    for (int k0 = 0; k0 < K; k0 += 32) {
      *(int4*)(&as[lrow][lch]) = *(const int4*)(&Ap[(size_t)(mBase + lrow) * lda + k0 + lch]);
      *(int4*)(&bs[lrow][lch]) = *(const int4*)(&Bp[(size_t)(nBase + lrow) * K + k0 + lch]);
      __syncthreads();
      int am = (w << 4) + (lane & 15);
      int kq = (lane >> 4) << 3;
      f16x8 af = *(const f16x8*)(&as[am][kq]);
#pragma unroll
      for (int nt = 0; nt < 4; nt++) {
        f16x8 bf = *(const f16x8*)(&bs[(nt << 4) + (lane & 15)][kq]);
        acc[nt] = __builtin_amdgcn_mfma_f32_16x16x32_f16(af, bf, acc[nt], 0, 0, 0);
      }
      __syncthreads();
    }
  }
  // C/D layout: col = lane&15, row = (lane>>4)*4 + reg
  int q = lane >> 4, c = lane & 15;
#pragma unroll
  for (int nt = 0; nt < 4; nt++)
#pragma unroll
    for (int r = 0; r < 4; r++) {
      int row = mBase + (w << 4) + (q << 2) + r;
      int col = nBase + (nt << 4) + c;
      G[(size_t)row * G4_ + col] = acc[nt][r];
    }
}

// ---------------- cell (LN + gates + c-LN + mask) ----------------

__device__ __forceinline__ void block_reduce(float* v, int n, float* sred, int tid) {
  int lane = tid & 63, w = tid >> 6;
  for (int off = 32; off > 0; off >>= 1)
    for (int i = 0; i < n; i++) v[i] += __shfl_down(v[i], off, 64);
  if (lane == 0)
    for (int i = 0; i < n; i++) sred[w * 4 + i] = v[i];
  __syncthreads();
  if (tid == 0)
    for (int i = 0; i < n; i++) sred[16 + i] = sred[i] + sred[4 + i] + sred[8 + i] + sred[12 + i];
  __syncthreads();
  for (int i = 0; i < n; i++) v[i] = sred[16 + i];
}

__device__ __forceinline__ float sigm(float x) { return 1.f / (1.f + expf(-x)); }

// h state carried as fp16 (hi,lo) pair: hHi = hP, hLo = hP + B*U. c state fp32.
__global__ __launch_bounds__(256) void cell_kernel(
    const float* __restrict__ Gx, const float* __restrict__ Gh,
    const float* __restrict__ bias, const float* __restrict__ kg, const float* __restrict__ kb,
    const float* __restrict__ rg, const float* __restrict__ rb,
    const float* __restrict__ sg, const float* __restrict__ sb,
    float* __restrict__ cS, _Float16* __restrict__ hP,
    _Float16* __restrict__ hnP, float* __restrict__ outb,
    const int* __restrict__ mask, int step) {
  int b = blockIdx.x, tid = threadIdx.x;
  __shared__ float sred[20];
  const float* gx = Gx + (size_t)b * G4_;
  const float* gh = Gh + (size_t)b * G4_;
  float vx[8], vh[8];
  float s[4] = {0.f, 0.f, 0.f, 0.f};
#pragma unroll
  for (int i = 0; i < 8; i++) {
    int col = tid + (i << 8);
    float a = gx[col], d = gh[col];
    vx[i] = a;
    vh[i] = d;
    s[0] += a;
    s[1] += a * a;
    s[2] += d;
    s[3] += d * d;
  }
  block_reduce(s, 4, sred, tid);
  const float inv = 1.f / 2048.f;
  float m1 = s[0] * inv, m2 = s[2] * inv;
  float rs1 = rsqrtf(fmaxf(s[1] * inv - m1 * m1, 0.f) + EPS_);
  float rs2 = rsqrtf(fmaxf(s[3] * inv - m2 * m2, 0.f) + EPS_);
  float z[8];
#pragma unroll
  for (int i = 0; i < 8; i++) {
    int col = tid + (i << 8);
    z[i] = (vx[i] - m1) * rs1 * kg[col] + kb[col] + (vh[i] - m2) * rs2 * rg[col] + rb[col] + bias[col];
  }
  // cols: i=0,1 -> i-gate (j0,j1); 2,3 -> f; 4,5 -> g; 6,7 -> o
  int j0 = tid, j1 = tid + 256;
  size_t base = (size_t)b * U_;
  _Float16* hHi = hP;
  _Float16* hLo = hP + (size_t)B_ * U_;
  float co0 = cS[base + j0], co1 = cS[base + j1];
  float cn0 = sigm(z[2]) * co0 + sigm(z[0]) * tanhf(z[4]);
  float cn1 = sigm(z[3]) * co1 + sigm(z[1]) * tanhf(z[5]);
  float t2[2] = {cn0 + cn1, cn0 * cn0 + cn1 * cn1};
  block_reduce(t2, 2, sred, tid);
  const float invU = 1.f / 512.f;
  float mc = t2[0] * invU;
  float rsc = rsqrtf(fmaxf(t2[1] * invU - mc * mc, 0.f) + EPS_);
  float cl0 = (cn0 - mc) * rsc * sg[j0] + sb[j0];
  float cl1 = (cn1 - mc) * rsc * sg[j1] + sb[j1];
  float hn0 = sigm(z[6]) * tanhf(cl0);
  float hn1 = sigm(z[7]) * tanhf(cl1);
  int mk = mask[(size_t)b * T_ + step];
  float ho0 = (float)hHi[base + j0] + (float)hLo[base + j0];
  float ho1 = (float)hHi[base + j1] + (float)hLo[base + j1];
  float hs0 = mk ? hn0 : ho0, hs1 = mk ? hn1 : ho1;
  _Float16 hh0 = (_Float16)hs0, hh1 = (_Float16)hs1;
  hHi[base + j0] = hh0;
  hLo[base + j0] = (_Float16)(hs0 - (float)hh0);
  hHi[base + j1] = hh1;
  hLo[base + j1] = (_Float16)(hs1 - (float)hh1);
  cS[base + j0] = mk ? cl0 : co0;
  cS[base + j1] = mk ? cl1 : co1;
  if (hnP) {  // layer-0: unmasked h_new feeds layer 1 (reference semantics)
    _Float16* nHi = hnP;
    _Float16* nLo = hnP + (size_t)B_ * U_;
    _Float16 n0 = (_Float16)hn0, n1 = (_Float16)hn1;
    nHi[base + j0] = n0;
    nLo[base + j0] = (_Float16)(hn0 - (float)n0);
    nHi[base + j1] = n1;
    nLo[base + j1] = (_Float16)(hn1 - (float)n1);
  }
  if (outb) {  // layer-1: out = mask ? hn : out_prev
    float oo0 = outb[base + j0], oo1 = outb[base + j1];
    outb[base + j0] = mk ? hn0 : oo0;
    outb[base + j1] = mk ? hn1 : oo1;
  }
}

// ---------------- final dense + softmax ----------------
__global__ __launch_bounds__(64) void dense_softmax_kernel(const float* __restrict__ outb,
                                                           const float* __restrict__ Wd,
                                                           const float* __restrict__ bd,
                                                           float* __restrict__ o) {
  int b = blockIdx.x, lane = threadIdx.x;
  __shared__ float sl[16];
  int col = lane & 15, kg = lane >> 4;
  float acc = 0.f;
  if (col < C_) {
    for (int k = kg; k < U_; k += 4) acc += outb[(size_t)b * U_ + k] * Wd[(size_t)k * C_ + col];
  }
  acc += __shfl_down(acc, 16, 64);
  acc += __shfl_down(acc, 32, 64);
  if (lane < C_) sl[lane] = acc + bd[lane];
  __syncthreads();
  if (lane < C_) {
    float mx = sl[0];
    for (int i = 1; i < C_; i++) mx = fmaxf(mx, sl[i]);
    float ssum = 0.f;
    for (int i = 0; i < C_; i++) ssum += expf(sl[i] - mx);
    o[(size_t)b * C_ + lane] = expf(sl[lane] - mx) / ssum;
  }
}

// ---------------- host ----------------

extern "C" void kernel_launch(void* const* d_in, const int* in_sizes, int n_in,
                              void* d_out, int out_size, void* d_ws, size_t ws_size,
                              hipStream_t stream) {
  const float* x = (const float*)d_in[0];
  const int* mask = (const int*)d_in[1];
  const float* W0 = (const float*)d_in[2];
  const float* R0 = (const float*)d_in[3];
  const float* b0 = (const float*)d_in[4];
  const float* kg0 = (const float*)d_in[5];
  const float* kb0 = (const float*)d_in[6];
  const float* rg0 = (const float*)d_in[7];
  const float* rb0 = (const float*)d_in[8];
  const float* sg0 = (const float*)d_in[9];
  const float* sb0 = (const float*)d_in[10];
  const float* W1 = (const float*)d_in[11];
  const float* R1 = (const float*)d_in[12];
  const float* b1 = (const float*)d_in[13];
  const float* kg1 = (const float*)d_in[14];
  const float* kb1 = (const float*)d_in[15];
  const float* rg1 = (const float*)d_in[16];
  const float* rb1 = (const float*)d_in[17];
  const float* sg1 = (const float*)d_in[18];
  const float* sb1 = (const float*)d_in[19];
  const float* Wd = (const float*)d_in[20];
  const float* bd = (const float*)d_in[21];
  float* out = (float*)d_out;

  char* w = (char*)d_ws;
  size_t o = 0;
  auto alloc = [&](size_t bytes) {
    size_t r = o;
    o += (bytes + 255) & ~(size_t)255;
    return r;
  };
  // zero region (contiguous, first)
  size_t o_c0s = alloc((size_t)B_ * U_ * 4);
  size_t o_c1s = alloc((size_t)B_ * U_ * 4);
  size_t o_outf = alloc((size_t)B_ * U_ * 4);
  size_t o_h0p = alloc((size_t)B_ * U_ * 2 * 2);  // hi + lo contiguous
  size_t o_h1p = alloc((size_t)B_ * U_ * 2 * 2);
  size_t zero_bytes = o;
  size_t o_hn0p = alloc((size_t)B_ * U_ * 2 * 2);
  size_t o_xh = alloc((size_t)T_ * B_ * FP_ * 2 * 2);  // hi + lo
  size_t o_W0t = alloc((size_t)G4_ * FP_ * 2 * 2);
  size_t o_R0t = alloc((size_t)G4_ * U_ * 2 * 2);
  size_t o_W1t = alloc((size_t)G4_ * U_ * 2 * 2);
  size_t o_R1t = alloc((size_t)G4_ * U_ * 2 * 2);
  size_t o_G0x = alloc((size_t)B_ * G4_ * 4);
  size_t o_G0h = alloc((size_t)B_ * G4_ * 4);
  size_t o_G1x = alloc((size_t)B_ * G4_ * 4);
  size_t o_G1h = alloc((size_t)B_ * G4_ * 4);
  (void)ws_size;

  float* c0s = (float*)(w + o_c0s);
  float* c1s = (float*)(w + o_c1s);
  float* outf = (float*)(w + o_outf);
  _Float16* h0p = (_Float16*)(w + o_h0p);
  _Float16* h1p = (_Float16*)(w + o_h1p);
  _Float16* hn0p = (_Float16*)(w + o_hn0p);
  _Float16* xh = (_Float16*)(w + o_xh);
  _Float16* W0t = (_Float16*)(w + o_W0t);
  _Float16* R0t = (_Float16*)(w + o_R0t);
  _Float16* W1t = (_Float16*)(w + o_W1t);
  _Float16* R1t = (_Float16*)(w + o_R1t);
  float* G0x = (float*)(w + o_G0x);
  float* G0h = (float*)(w + o_G0h);
  float* G1x = (float*)(w + o_G1x);
  float* G1h = (float*)(w + o_G1h);

  hipMemsetAsync(w, 0, zero_bytes, stream);

  {
    size_t total = (size_t)T_ * B_ * FP_;
    cast_x_kernel<<<dim3((unsigned)(total / 256)), 256, 0, stream>>>(
        x, xh, xh + total);
  }
  cast_w_kernel<<<dim3(G4_ / 32, FP_ / 32), 256, 0, stream>>>(
      W0, W0t, W0t + (size_t)G4_ * FP_, F_, G4_, FP_);
  cast_w_kernel<<<dim3(G4_ / 32, U_ / 32), 256, 0, stream>>>(
      R0, R0t, R0t + (size_t)G4_ * U_, U_, G4_, U_);
  cast_w_kernel<<<dim3(G4_ / 32, U_ / 32), 256, 0, stream>>>(
      W1, W1t, W1t + (size_t)G4_ * U_, U_, G4_, U_);
  cast_w_kernel<<<dim3(G4_ / 32, U_ / 32), 256, 0, stream>>>(
      R1, R1t, R1t + (size_t)G4_ * U_, U_, G4_, U_);

  dim3 ggrid3(G4_ / 64, B_ / 64, 3);
  dim3 ggrid1(G4_ / 64, B_ / 64, 1);
  const size_t xLoOff = (size_t)T_ * B_ * FP_;
  const size_t hLoOff = (size_t)B_ * U_;

  for (int t = 0; t < T_; t++) {
    const _Float16* xt = xh + (size_t)t * B_ * FP_;
    // G0x = x_t @ W0 ; G0h = h0 @ R0 ; G1h = h1 @ R1   (independent)
    gemm3_kernel<<<ggrid3, 256, 0, stream>>>(
        xt, W0t, G0x, FP_, FP_, xLoOff,
        h0p, R0t, G0h, U_, U_, hLoOff,
        h1p, R1t, G1h, U_, U_, hLoOff);
    cell_kernel<<<B_, 256, 0, stream>>>(G0x, G0h, b0, kg0, kb0, rg0, rb0, sg0, sb0,
                                        c0s, h0p, hn0p, (float*)nullptr, mask, t);
    // G1x = hn0 @ W1
    gemm3_kernel<<<ggrid1, 256, 0, stream>>>(
        hn0p, W1t, G1x, U_, U_, hLoOff,
        hn0p, W1t, G1x, U_, U_, hLoOff,
        hn0p, W1t, G1x, U_, U_, hLoOff);
    cell_kernel<<<B_, 256, 0, stream>>>(G1x, G1h, b1, kg1, kb1, rg1, rb1, sg1, sb1,
                                        c1s, h1p, (_Float16*)nullptr, outf, mask, t);
  }

  dense_softmax_kernel<<<B_, 64, 0, stream>>>(outf, Wd, bd, out);
}

// Round 3
// 7345.914 us; speedup vs baseline: 1.2236x; 1.2236x over previous
//
#include <hip/hip_runtime.h>

#define B_ 1024
#define T_ 100
#define F_ 300
#define FP_ 320
#define U_ 512
#define G4_ 2048
#define C_ 10
#define EPS_ 1e-3f

typedef _Float16 f16x8 __attribute__((ext_vector_type(8)));
typedef float f32x4 __attribute__((ext_vector_type(4)));

typedef __attribute__((address_space(1))) const void* gcptr_t;
typedef __attribute__((address_space(3))) void* lptr_t;

__device__ __forceinline__ void async_ld16(_Float16* lds, const _Float16* g) {
  __builtin_amdgcn_global_load_lds((gcptr_t)g, (lptr_t)lds, 16, 0, 0);
}

// ---------------- prologue kernels ----------------

// x (B,T,F) fp32 -> x_hi/x_lo [T][B][FP_] fp16 split, zero-padded F..FP_
__global__ __launch_bounds__(256) void cast_x_kernel(const float* __restrict__ x,
                                                     _Float16* __restrict__ xhi,
                                                     _Float16* __restrict__ xlo) {
  size_t idx = (size_t)blockIdx.x * 256 + threadIdx.x;
  int f = (int)(idx % FP_);
  size_t bt = idx / FP_;
  int b = (int)(bt % B_);
  int t = (int)(bt / B_);
  float v = 0.f;
  if (f < F_) v = x[((size_t)b * T_ + t) * F_ + f];
  _Float16 h = (_Float16)v;
  xhi[idx] = h;
  xlo[idx] = (_Float16)(v - (float)h);
}

// W [K][N] fp32 -> Wt_hi/Wt_lo [N][Kp] fp16 split (transposed, zero-padded K..Kp)
__global__ __launch_bounds__(256) void cast_w_kernel(const float* __restrict__ W,
                                                     _Float16* __restrict__ Whi,
                                                     _Float16* __restrict__ Wlo,
                                                     int K, int N, int Kp) {
  __shared__ float tile[32][33];
  int n0 = blockIdx.x * 32, k0 = blockIdx.y * 32;
  int tx = threadIdx.x & 31, ty = threadIdx.x >> 5;
#pragma unroll
  for (int r = 0; r < 32; r += 8) {
    int k = k0 + ty + r;
    tile[ty + r][tx] = (k < K) ? W[(size_t)k * N + n0 + tx] : 0.f;
  }
  __syncthreads();
#pragma unroll
  for (int r = 0; r < 32; r += 8) {
    int n = n0 + ty + r, kk = k0 + tx;
    if (kk < Kp) {
      float v = tile[tx][ty + r];
      _Float16 h = (_Float16)v;
      Whi[(size_t)n * Kp + kk] = h;
      Wlo[(size_t)n * Kp + kk] = (_Float16)(v - (float)h);
    }
  }
}

// ---------------- GEMM: G = A (MxK) * Bt^T (Bt is [N][K]) -> G [M][2048] fp32 --------
// Split-fp16 3-segment: A_hi@B_hi + A_lo@B_hi + A_hi@B_lo. G output fp32.
// Block tile 64(M)x128(N), BK=64, 128 threads = 2 waves, wave tile 64x64.
// Staging: global_load_lds 16B, LDS chunk layout XOR-swizzled on the global side
// (16B chunk p of row r holds logical chunk p^(r&7)) -> conflict-free ds_read_b128.
// Up to 3 independent GEMMs via blockIdx.z.
__global__ __launch_bounds__(128) void gemm3_kernel(
    const _Float16* __restrict__ A0, const _Float16* __restrict__ Bt0, float* __restrict__ G0, int lda0, int K0, size_t aLo0,
    const _Float16* __restrict__ A1, const _Float16* __restrict__ Bt1, float* __restrict__ G1, int lda1, int K1, size_t aLo1,
    const _Float16* __restrict__ A2, const _Float16* __restrict__ Bt2, float* __restrict__ G2, int lda2, int K2, size_t aLo2) {
  const _Float16* A;
  const _Float16* Bt;
  float* G;
  int lda, K;
  size_t aLo;
  if (blockIdx.z == 0) { A = A0; Bt = Bt0; G = G0; lda = lda0; K = K0; aLo = aLo0; }
  else if (blockIdx.z == 1) { A = A1; Bt = Bt1; G = G1; lda = lda1; K = K1; aLo = aLo1; }
  else { A = A2; Bt = Bt2; G = G2; lda = lda2; K = K2; aLo = aLo2; }

  __shared__ __align__(16) _Float16 as[64][64];   // 8 KB
  __shared__ __align__(16) _Float16 bs[128][64];  // 16 KB

  const int tid = threadIdx.x;
  const int w = tid >> 6;  // 0..1
  const int lane = tid & 63;
  const int mBase = blockIdx.y * 64, nBase = blockIdx.x * 128;
  const int wn = w << 6;

  f32x4 acc[4][4];
#pragma unroll
  for (int mt = 0; mt < 4; mt++)
#pragma unroll
    for (int nt = 0; nt < 4; nt++) acc[mt][nt] = (f32x4){0.f, 0.f, 0.f, 0.f};

  const size_t bLo = (size_t)G4_ * K;
#pragma unroll 1
  for (int s = 0; s < 3; s++) {
    const _Float16* Ap = A + ((s == 1) ? aLo : 0);
    const _Float16* Bp = Bt + ((s == 2) ? bLo : 0);
#pragma unroll 1
    for (int k0 = 0; k0 < K; k0 += 64) {
      // stage A: 8 issues total (4 per wave), each 64 lanes x 16B
#pragma unroll
      for (int j = 0; j < 4; j++) {
        int i = (w << 2) + j;
        int idx = (i << 6) + lane;
        int row = idx >> 3;
        int cl = ((idx & 7) ^ (row & 7)) << 3;
        async_ld16(&as[0][0] + (i << 9),
                   Ap + (size_t)(mBase + row) * lda + k0 + cl);
      }
      // stage B: 16 issues total (8 per wave)
#pragma unroll
      for (int j = 0; j < 8; j++) {
        int i = (w << 3) + j;
        int idx = (i << 6) + lane;
        int row = idx >> 3;
        int cl = ((idx & 7) ^ (row & 7)) << 3;
        async_ld16(&bs[0][0] + (i << 9),
                   Bp + (size_t)(nBase + row) * K + k0 + cl);
      }
      __syncthreads();
#pragma unroll
      for (int q = 0; q < 2; q++) {
        f16x8 af[4], bf[4];
#pragma unroll
        for (int mt = 0; mt < 4; mt++) {
          int row = (mt << 4) + (lane & 15);
          int p = ((q << 2) + (lane >> 4)) ^ (row & 7);
          af[mt] = *(const f16x8*)&as[row][p << 3];
        }
#pragma unroll
        for (int nt = 0; nt < 4; nt++) {
          int row = wn + (nt << 4) + (lane & 15);
          int p = ((q << 2) + (lane >> 4)) ^ (row & 7);
          bf[nt] = *(const f16x8*)&bs[row][p << 3];
        }
#pragma unroll
        for (int mt = 0; mt < 4; mt++)
#pragma unroll
          for (int nt = 0; nt < 4; nt++)
            acc[mt][nt] = __builtin_amdgcn_mfma_f32_16x16x32_f16(af[mt], bf[nt], acc[mt][nt], 0, 0, 0);
      }
      __syncthreads();
    }
  }
  // C/D layout: col = lane&15, row = (lane>>4)*4 + reg
  int q = lane >> 4, c = lane & 15;
#pragma unroll
  for (int mt = 0; mt < 4; mt++)
#pragma unroll
    for (int nt = 0; nt < 4; nt++)
#pragma unroll
      for (int r = 0; r < 4; r++) {
        int row = mBase + (mt << 4) + (q << 2) + r;
        int col = nBase + wn + (nt << 4) + c;
        G[(size_t)row * G4_ + col] = acc[mt][nt][r];
      }
}

// ---------------- cell (LN + gates + c-LN + mask) ----------------

__device__ __forceinline__ void block_reduce(float* v, int n, float* sred, int tid) {
  int lane = tid & 63, w = tid >> 6;
  for (int off = 32; off > 0; off >>= 1)
    for (int i = 0; i < n; i++) v[i] += __shfl_down(v[i], off, 64);
  if (lane == 0)
    for (int i = 0; i < n; i++) sred[w * 4 + i] = v[i];
  __syncthreads();
  if (tid == 0)
    for (int i = 0; i < n; i++) sred[16 + i] = sred[i] + sred[4 + i] + sred[8 + i] + sred[12 + i];
  __syncthreads();
  for (int i = 0; i < n; i++) v[i] = sred[16 + i];
}

__device__ __forceinline__ float sigm(float x) { return 1.f / (1.f + expf(-x)); }

// h state carried as fp16 (hi,lo) pair: hHi = hP, hLo = hP + B*U. c state fp32.
__global__ __launch_bounds__(256) void cell_kernel(
    const float* __restrict__ Gx, const float* __restrict__ Gh,
    const float* __restrict__ bias, const float* __restrict__ kg, const float* __restrict__ kb,
    const float* __restrict__ rg, const float* __restrict__ rb,
    const float* __restrict__ sg, const float* __restrict__ sb,
    float* __restrict__ cS, _Float16* __restrict__ hP,
    _Float16* __restrict__ hnP, float* __restrict__ outb,
    const int* __restrict__ mask, int step) {
  int b = blockIdx.x, tid = threadIdx.x;
  __shared__ float sred[20];
  const float* gx = Gx + (size_t)b * G4_;
  const float* gh = Gh + (size_t)b * G4_;
  float vx[8], vh[8];
  float s[4] = {0.f, 0.f, 0.f, 0.f};
#pragma unroll
  for (int i = 0; i < 8; i++) {
    int col = tid + (i << 8);
    float a = gx[col], d = gh[col];
    vx[i] = a;
    vh[i] = d;
    s[0] += a;
    s[1] += a * a;
    s[2] += d;
    s[3] += d * d;
  }
  block_reduce(s, 4, sred, tid);
  const float inv = 1.f / 2048.f;
  float m1 = s[0] * inv, m2 = s[2] * inv;
  float rs1 = rsqrtf(fmaxf(s[1] * inv - m1 * m1, 0.f) + EPS_);
  float rs2 = rsqrtf(fmaxf(s[3] * inv - m2 * m2, 0.f) + EPS_);
  float z[8];
#pragma unroll
  for (int i = 0; i < 8; i++) {
    int col = tid + (i << 8);
    z[i] = (vx[i] - m1) * rs1 * kg[col] + kb[col] + (vh[i] - m2) * rs2 * rg[col] + rb[col] + bias[col];
  }
  // cols: i=0,1 -> i-gate (j0,j1); 2,3 -> f; 4,5 -> g; 6,7 -> o
  int j0 = tid, j1 = tid + 256;
  size_t base = (size_t)b * U_;
  _Float16* hHi = hP;
  _Float16* hLo = hP + (size_t)B_ * U_;
  float co0 = cS[base + j0], co1 = cS[base + j1];
  float cn0 = sigm(z[2]) * co0 + sigm(z[0]) * tanhf(z[4]);
  float cn1 = sigm(z[3]) * co1 + sigm(z[1]) * tanhf(z[5]);
  float t2[2] = {cn0 + cn1, cn0 * cn0 + cn1 * cn1};
  block_reduce(t2, 2, sred, tid);
  const float invU = 1.f / 512.f;
  float mc = t2[0] * invU;
  float rsc = rsqrtf(fmaxf(t2[1] * invU - mc * mc, 0.f) + EPS_);
  float cl0 = (cn0 - mc) * rsc * sg[j0] + sb[j0];
  float cl1 = (cn1 - mc) * rsc * sg[j1] + sb[j1];
  float hn0 = sigm(z[6]) * tanhf(cl0);
  float hn1 = sigm(z[7]) * tanhf(cl1);
  int mk = mask[(size_t)b * T_ + step];
  float ho0 = (float)hHi[base + j0] + (float)hLo[base + j0];
  float ho1 = (float)hHi[base + j1] + (float)hLo[base + j1];
  float hs0 = mk ? hn0 : ho0, hs1 = mk ? hn1 : ho1;
  _Float16 hh0 = (_Float16)hs0, hh1 = (_Float16)hs1;
  hHi[base + j0] = hh0;
  hLo[base + j0] = (_Float16)(hs0 - (float)hh0);
  hHi[base + j1] = hh1;
  hLo[base + j1] = (_Float16)(hs1 - (float)hh1);
  cS[base + j0] = mk ? cl0 : co0;
  cS[base + j1] = mk ? cl1 : co1;
  if (hnP) {  // layer-0: unmasked h_new feeds layer 1 (reference semantics)
    _Float16* nHi = hnP;
    _Float16* nLo = hnP + (size_t)B_ * U_;
    _Float16 n0 = (_Float16)hn0, n1 = (_Float16)hn1;
    nHi[base + j0] = n0;
    nLo[base + j0] = (_Float16)(hn0 - (float)n0);
    nHi[base + j1] = n1;
    nLo[base + j1] = (_Float16)(hn1 - (float)n1);
  }
  if (outb) {  // layer-1: out = mask ? hn : out_prev
    float oo0 = outb[base + j0], oo1 = outb[base + j1];
    outb[base + j0] = mk ? hn0 : oo0;
    outb[base + j1] = mk ? hn1 : oo1;
  }
}

// ---------------- final dense + softmax ----------------
__global__ __launch_bounds__(64) void dense_softmax_kernel(const float* __restrict__ outb,
                                                           const float* __restrict__ Wd,
                                                           const float* __restrict__ bd,
                                                           float* __restrict__ o) {
  int b = blockIdx.x, lane = threadIdx.x;
  __shared__ float sl[16];
  int col = lane & 15, kg = lane >> 4;
  float acc = 0.f;
  if (col < C_) {
    for (int k = kg; k < U_; k += 4) acc += outb[(size_t)b * U_ + k] * Wd[(size_t)k * C_ + col];
  }
  acc += __shfl_down(acc, 16, 64);
  acc += __shfl_down(acc, 32, 64);
  if (lane < C_) sl[lane] = acc + bd[lane];
  __syncthreads();
  if (lane < C_) {
    float mx = sl[0];
    for (int i = 1; i < C_; i++) mx = fmaxf(mx, sl[i]);
    float ssum = 0.f;
    for (int i = 0; i < C_; i++) ssum += expf(sl[i] - mx);
    o[(size_t)b * C_ + lane] = expf(sl[lane] - mx) / ssum;
  }
}

// ---------------- host ----------------

extern "C" void kernel_launch(void* const* d_in, const int* in_sizes, int n_in,
                              void* d_out, int out_size, void* d_ws, size_t ws_size,
                              hipStream_t stream) {
  const float* x = (const float*)d_in[0];
  const int* mask = (const int*)d_in[1];
  const float* W0 = (const float*)d_in[2];
  const float* R0 = (const float*)d_in[3];
  const float* b0 = (const float*)d_in[4];
  const float* kg0 = (const float*)d_in[5];
  const float* kb0 = (const float*)d_in[6];
  const float* rg0 = (const float*)d_in[7];
  const float* rb0 = (const float*)d_in[8];
  const float* sg0 = (const float*)d_in[9];
  const float* sb0 = (const float*)d_in[10];
  const float* W1 = (const float*)d_in[11];
  const float* R1 = (const float*)d_in[12];
  const float* b1 = (const float*)d_in[13];
  const float* kg1 = (const float*)d_in[14];
  const float* kb1 = (const float*)d_in[15];
  const float* rg1 = (const float*)d_in[16];
  const float* rb1 = (const float*)d_in[17];
  const float* sg1 = (const float*)d_in[18];
  const float* sb1 = (const float*)d_in[19];
  const float* Wd = (const float*)d_in[20];
  const float* bd = (const float*)d_in[21];
  float* out = (float*)d_out;

  char* w = (char*)d_ws;
  size_t o = 0;
  auto alloc = [&](size_t bytes) {
    size_t r = o;
    o += (bytes + 255) & ~(size_t)255;
    return r;
  };
  // zero region (contiguous, first)
  size_t o_c0s = alloc((size_t)B_ * U_ * 4);
  size_t o_c1s = alloc((size_t)B_ * U_ * 4);
  size_t o_outf = alloc((size_t)B_ * U_ * 4);
  size_t o_h0p = alloc((size_t)B_ * U_ * 2 * 2);  // hi + lo contiguous
  size_t o_h1p = alloc((size_t)B_ * U_ * 2 * 2);
  size_t zero_bytes = o;
  size_t o_hn0p = alloc((size_t)B_ * U_ * 2 * 2);
  size_t o_xh = alloc((size_t)T_ * B_ * FP_ * 2 * 2);  // hi + lo
  size_t o_W0t = alloc((size_t)G4_ * FP_ * 2 * 2);
  size_t o_R0t = alloc((size_t)G4_ * U_ * 2 * 2);
  size_t o_W1t = alloc((size_t)G4_ * U_ * 2 * 2);
  size_t o_R1t = alloc((size_t)G4_ * U_ * 2 * 2);
  size_t o_G0x = alloc((size_t)B_ * G4_ * 4);
  size_t o_G0h = alloc((size_t)B_ * G4_ * 4);
  size_t o_G1x = alloc((size_t)B_ * G4_ * 4);
  size_t o_G1h = alloc((size_t)B_ * G4_ * 4);
  (void)ws_size;

  float* c0s = (float*)(w + o_c0s);
  float* c1s = (float*)(w + o_c1s);
  float* outf = (float*)(w + o_outf);
  _Float16* h0p = (_Float16*)(w + o_h0p);
  _Float16* h1p = (_Float16*)(w + o_h1p);
  _Float16* hn0p = (_Float16*)(w + o_hn0p);
  _Float16* xh = (_Float16*)(w + o_xh);
  _Float16* W0t = (_Float16*)(w + o_W0t);
  _Float16* R0t = (_Float16*)(w + o_R0t);
  _Float16* W1t = (_Float16*)(w + o_W1t);
  _Float16* R1t = (_Float16*)(w + o_R1t);
  float* G0x = (float*)(w + o_G0x);
  float* G0h = (float*)(w + o_G0h);
  float* G1x = (float*)(w + o_G1x);
  float* G1h = (float*)(w + o_G1h);

  hipMemsetAsync(w, 0, zero_bytes, stream);

  {
    size_t total = (size_t)T_ * B_ * FP_;
    cast_x_kernel<<<dim3((unsigned)(total / 256)), 256, 0, stream>>>(
        x, xh, xh + total);
  }
  cast_w_kernel<<<dim3(G4_ / 32, FP_ / 32), 256, 0, stream>>>(
      W0, W0t, W0t + (size_t)G4_ * FP_, F_, G4_, FP_);
  cast_w_kernel<<<dim3(G4_ / 32, U_ / 32), 256, 0, stream>>>(
      R0, R0t, R0t + (size_t)G4_ * U_, U_, G4_, U_);
  cast_w_kernel<<<dim3(G4_ / 32, U_ / 32), 256, 0, stream>>>(
      W1, W1t, W1t + (size_t)G4_ * U_, U_, G4_, U_);
  cast_w_kernel<<<dim3(G4_ / 32, U_ / 32), 256, 0, stream>>>(
      R1, R1t, R1t + (size_t)G4_ * U_, U_, G4_, U_);

  dim3 ggrid3(G4_ / 128, B_ / 64, 3);
  dim3 ggrid1(G4_ / 128, B_ / 64, 1);
  const size_t xLoOff = (size_t)T_ * B_ * FP_;
  const size_t hLoOff = (size_t)B_ * U_;

  for (int t = 0; t < T_; t++) {
    const _Float16* xt = xh + (size_t)t * B_ * FP_;
    // G0x = x_t @ W0 ; G0h = h0 @ R0 ; G1h = h1 @ R1   (independent)
    gemm3_kernel<<<ggrid3, 128, 0, stream>>>(
        xt, W0t, G0x, FP_, FP_, xLoOff,
        h0p, R0t, G0h, U_, U_, hLoOff,
        h1p, R1t, G1h, U_, U_, hLoOff);
    cell_kernel<<<B_, 256, 0, stream>>>(G0x, G0h, b0, kg0, kb0, rg0, rb0, sg0, sb0,
                                        c0s, h0p, hn0p, (float*)nullptr, mask, t);
    // G1x = hn0 @ W1
    gemm3_kernel<<<ggrid1, 128, 0, stream>>>(
        hn0p, W1t, G1x, U_, U_, hLoOff,
        hn0p, W1t, G1x, U_, U_, hLoOff,
        hn0p, W1t, G1x, U_, U_, hLoOff);
    cell_kernel<<<B_, 256, 0, stream>>>(G1x, G1h, b1, kg1, kb1, rg1, rb1, sg1, sb1,
                                        c1s, h1p, (_Float16*)nullptr, outf, mask, t);
  }

  dense_softmax_kernel<<<B_, 64, 0, stream>>>(outf, Wd, bd, out);
}